// Round 15
// baseline (765.936 us; speedup 1.0000x reference)
//
#include <hip/hip_runtime.h>

#define NN 20000
#define NE 200000
#define NG 512

typedef float v2f __attribute__((ext_vector_type(2)));

struct TrueC { static constexpr bool value = true;  };
struct FalseC{ static constexpr bool value = false; };

__device__ __forceinline__ int lowerb(const int* a, int n, int v){
  int lo=0, hi=n;
  while(lo<hi){ int m=(lo+hi)>>1; if(a[m]<v) lo=m+1; else hi=m; }
  return lo;
}

// async global->LDS copy, 16B per lane. LDS dest must be linear in lane order
// (wave-uniform base + lane*16).
template<int AUX>
__device__ __forceinline__ void gload_lds16(const float4* g, float4* l){
  __builtin_amdgcn_global_load_lds(
    (const __attribute__((address_space(1))) void*)(g),
    (__attribute__((address_space(3))) void*)(l), 16, 0, AUX);
}

// ---------------- counting sort by tgt -> CSR ----------------
__global__ void k_count(const int* __restrict__ tgt, int* __restrict__ cnt){
  int e = blockIdx.x*blockDim.x + threadIdx.x;
  if(e<NE) atomicAdd(&cnt[tgt[e]], 1);
}

__global__ void k_scan(const int* __restrict__ cnt, int* __restrict__ row_start){
  __shared__ int part[1024];
  int t = threadIdx.x;
  const int CH = (NN + 1023)/1024; // 20
  int i0 = t*CH;
  int s = 0;
  for(int j=0;j<CH;j++){ int i=i0+j; if(i<NN) s += cnt[i]; }
  part[t] = s; __syncthreads();
  for(int d=1; d<1024; d<<=1){
    int v = (t>=d) ? part[t-d] : 0;
    __syncthreads();
    part[t] += v;
    __syncthreads();
  }
  int run = (t==0) ? 0 : part[t-1];
  for(int j=0;j<CH;j++){ int i=i0+j; if(i<NN){ row_start[i]=run; run += cnt[i]; } }
  if(t==0) row_start[NN] = part[1023];
}

// place edges in CSR order AND gather edge_attr to CSR order (fused)
__global__ void k_place(const int* __restrict__ src, const int* __restrict__ tgt,
                        const float* __restrict__ ea,
                        const int* __restrict__ row_start, int* __restrict__ cur,
                        int* __restrict__ es_src, float* __restrict__ es_ea){
  int e = blockIdx.x*blockDim.x + threadIdx.x;
  if(e>=NE) return;
  int n = tgt[e];
  int pos = row_start[n] + atomicAdd(&cur[n],1);
  es_src[pos] = src[e];
  const float4* s = (const float4*)ea + (size_t)e*4;
  float4* d = (float4*)es_ea + (size_t)pos*4;
  d[0]=s[0]; d[1]=s[1]; d[2]=s[2]; d[3]=s[3];
}

// ---------------- fused NNConv layer ----------------
// Round 15 = EXACT round-13 layer (best: 692us) + ONLY the low-risk half of round 14:
// xsum accumulated only in split-0 blocks (two if-constexpr instantiations of the
// UNCHANGED rotation-style scatter; uniform block branch, no new live ranges).
// Round-14 lesson (re-learning round 1): A/B duplicated register sets live across a
// runtime loop back-edge => scratch spill (WRITE 13.75->242MB, FETCH +68MB, dur +21us)
// even though reported VGPR stayed 84 -- spills don't raise VGPR_Count. The rotation
// movs are the cheap price for bounded liveness; keep them.
// Prior lessons intact: H/xbar fusion + packed H (rounds 12/13), dead-S combine
// (round 13), PF scatter prefetch + W2-only ping-pong (rounds 2/8; S reads
// in-iteration per round 1), BN=8 for L1/L2 (round 7), no min-waves>3 (rounds 4/5),
// exact-multiple staging regions (async-tail overlap = race).
// No-spill check: FETCH ~64MB, WRITE ~14MB, VGPR ~84. Any deviation => revert to r13.
template<int IC, int OC, int PLEN, int KS, int BN, int PP, int TI, int OQ, int TO, bool PF, int EB>
__launch_bounds__(256, 3)
__global__ void k_layer(const float* __restrict__ x_in, const float* __restrict__ es_ea,
                        const int* __restrict__ es_src, const int* __restrict__ row_start,
                        const float* __restrict__ W1, const float* __restrict__ b1,
                        const float* __restrict__ W2, float* __restrict__ part,
                        float* __restrict__ xbar_out)
{
  constexpr int K    = PLEN*IC;
  constexpr int XV   = IC/4;
  constexpr int NIW  = IC/TI;
  constexpr int NPW  = PLEN/PP;
  constexpr int G    = BN/4;
  constexpr int KQL  = 64/OQ;
  constexpr int TSPL = 4*KQL;
  constexpr int J    = (K/4)/TSPL;
  constexpr int NEA  = EB/64;            // ea staging chunks (EB*16/4/256)
  constexpr int NX4  = (EB*XV)/256;      // xs staging chunks (exact)
  constexpr int TI2  = TI/2;
  constexpr int NP   = TO/2;
  constexpr bool TODD = (TO & 1);
  constexpr int HP   = PLEN/2;           // column pairs per H-compute thread
  constexpr int EPB2 = 256/HP;           // edges per packed H-compute iteration
  static_assert(TI%2==0, "packed scatter needs even TI");
  static_assert(256%HP==0, "packed H-compute mapping");
  static_assert(EB%64==0, "ea region must be exact 256-f4 chunks");
  static_assert((EB*XV)%256==0, "xs region must be exact 256-f4 chunks");
  static_assert(EB*(PLEN+16+IC) <= BN*K, "staging alias fits in S");
  static_assert(NPW*NIW==64, "wave tile covers 64 lanes");
  static_assert(G*PP*TI <= 48, "spill-safe accumulator");
  static_assert(OQ*TO==OC && (K/4)%TSPL==0, "gemm tiling");
  static_assert(J%2==0, "ping-pong needs even J");
  static_assert(3*BN*OC <= BN*K, "combine area fits in dead S");

  __shared__ __align__(16) float S[BN*K];
  __shared__ int rs_s[BN+1], ro[BN+1];

  float* hb  = S;                        // EB*PLEN computed H slice
  float* eas = S + EB*PLEN;              // EB*16 staged edge_attr
  float* xs  = S + EB*(PLEN+16);         // EB*IC staged x[src]

  const int tid = threadIdx.x;
  const int wid = tid>>6, lane = tid&63;
  const int split = blockIdx.x % KS;
  const int nb = blockIdx.x / KS;
  const int n0 = nb*BN;

  if(tid<=BN) rs_s[tid] = row_start[n0+tid];
  __syncthreads();
  const int estart = rs_s[0], eend = rs_s[BN];

  const int pw = lane / NIW;
  const int iw = lane - pw*NIW;
  const int c2 = tid % HP, erow = tid / HP;

  // per-split W1 column PAIR + bias pair (hoisted; coalesced loads)
  v2f w1cp[16];
  const v2f b1cp = *(const v2f*)&b1[split*PLEN + 2*c2];
  #pragma unroll
  for(int i=0;i<16;i++) w1cp[i] = *(const v2f*)&W1[i*128 + split*PLEN + 2*c2];

  v2f acc2[G][PP][TI2];
  v2f xsum2[G][TI2];
  #pragma unroll
  for(int g=0;g<G;g++){
    #pragma unroll
    for(int p=0;p<PP;p++)
      #pragma unroll
      for(int u=0;u<TI2;u++) acc2[g][p][u]=v2f{0.f,0.f};
    #pragma unroll
    for(int u=0;u<TI2;u++) xsum2[g][u]=v2f{0.f,0.f};
  }

  const float4* EA4 = (const float4*)es_ea;
  const float4* x4  = (const float4*)x_in;

  for(int bstart=estart; bstart<eend; bstart+=EB){
    const int ebc = min(EB, eend-bstart);
    if(tid<=BN){ int v = rs_s[tid]-bstart; ro[tid] = min(max(v,0), ebc); }
    const int ea_lim = ebc*4, xs_lim = ebc*XV;
    // pre-load gather indices (independent loads, issued together)
    int sn_r[NX4];
    #pragma unroll
    for(int c=0;c<NX4;c++){
      int jc = min(tid + c*256, xs_lim-1);
      sn_r[c] = es_src[bstart + jc/XV];
    }
    // async edge_attr -> eas (CSR-linear source)
    #pragma unroll
    for(int c=0;c<NEA;c++){
      int j = tid + c*256;
      int jc = min(j, ea_lim-1);
      gload_lds16<0>(EA4 + (size_t)bstart*4 + jc, ((float4*)eas) + j);
    }
    // async x[src] -> xs
    #pragma unroll
    for(int c=0;c<NX4;c++){
      int j = tid + c*256;
      int jc = min(j, xs_lim-1);
      int q = jc - (jc/XV)*XV;
      gload_lds16<0>(x4 + (size_t)sn_r[c]*XV + q, ((float4*)xs) + j);
    }
    __syncthreads();   // drains vmcnt (global_load_lds tracked there)

    // ---- compute H slice (packed column pairs): h[e][2c2..2c2+1] ----
    for(int ec = erow; ec < ebc; ec += EPB2){
      v2f h = b1cp;
      #pragma unroll
      for(int q=0;q<4;q++){
        float4 a = *(const float4*)&eas[ec*16 + 4*q];   // broadcast within group
        h += v2f{a.x,a.x}*w1cp[4*q+0];
        h += v2f{a.y,a.y}*w1cp[4*q+1];
        h += v2f{a.z,a.z}*w1cp[4*q+2];
        h += v2f{a.w,a.w}*w1cp[4*q+3];
      }
      h[0] = fmaxf(h[0],0.f); h[1] = fmaxf(h[1],0.f);
      *(v2f*)&hb[ec*PLEN + 2*c2] = h;
    }
    __syncthreads();

    // ---- wave-private scatter (round-13 rotation pipeline, unchanged) ----
    auto scatter = [&](auto XSC){
      constexpr bool XS = decltype(XSC)::value;
      if constexpr (PF){
        #pragma unroll
        for(int g=0; g<G; g++){
          const int nl = wid*G + g;
          const int a = ro[nl], b = ro[nl+1];
          if(a>=b) continue;
          float hv[PP]; v2f xv2[TI2];
          #pragma unroll
          for(int p=0;p<PP;p++) hv[p] = hb[a*PLEN + pw*PP + p];
          #pragma unroll
          for(int u=0;u<TI2;u++) xv2[u] = *(const v2f*)&xs[a*IC + iw*TI + 2*u];
          for(int e=a; e<b; e++){
            float hn[PP]; v2f xn2[TI2];
            if(e+1<b){
              #pragma unroll
              for(int p=0;p<PP;p++) hn[p] = hb[(e+1)*PLEN + pw*PP + p];
              #pragma unroll
              for(int u=0;u<TI2;u++) xn2[u] = *(const v2f*)&xs[(e+1)*IC + iw*TI + 2*u];
            }
            #pragma unroll
            for(int p=0;p<PP;p++){
              v2f h2 = v2f{hv[p], hv[p]};
              #pragma unroll
              for(int u=0;u<TI2;u++) acc2[g][p][u] += h2*xv2[u];
            }
            if constexpr (XS){
              #pragma unroll
              for(int u=0;u<TI2;u++) xsum2[g][u] += xv2[u];
            }
            #pragma unroll
            for(int p=0;p<PP;p++) hv[p]=hn[p];
            #pragma unroll
            for(int u=0;u<TI2;u++) xv2[u]=xn2[u];
          }
        }
      } else {
        #pragma unroll
        for(int g=0; g<G; g++){
          const int nl = wid*G + g;
          const int a = ro[nl], b = ro[nl+1];
          for(int e=a; e<b; e++){
            float hv[PP];
            #pragma unroll
            for(int p=0;p<PP;p++) hv[p] = hb[e*PLEN + pw*PP + p];
            v2f xv2[TI2];
            #pragma unroll
            for(int u=0;u<TI2;u++) xv2[u] = *(const v2f*)&xs[e*IC + iw*TI + 2*u];
            #pragma unroll
            for(int p=0;p<PP;p++){
              v2f h2 = v2f{hv[p], hv[p]};
              #pragma unroll
              for(int u=0;u<TI2;u++) acc2[g][p][u] += h2*xv2[u];
            }
            if constexpr (XS){
              #pragma unroll
              for(int u=0;u<TI2;u++) xsum2[g][u] += xv2[u];
            }
          }
        }
      }
    };
    if(split==0) scatter(TrueC{}); else scatter(FalseC{});
    __syncthreads();
  }

  // xbar write (split 0 only; pw==0 lanes hold the full iw-slice sums)
  if(split==0 && pw==0){
    #pragma unroll
    for(int g=0;g<G;g++){
      const int nl = wid*G + g;
      const float dv = 1.f/fmaxf((float)(rs_s[nl+1]-rs_s[nl]), 1.f);
      #pragma unroll
      for(int u=0;u<TI2;u++){
        v2f r = xsum2[g][u]*v2f{dv,dv};
        *(v2f*)&xbar_out[(size_t)(n0+nl)*IC + iw*TI + 2*u] = r;
      }
    }
  }

  // dump scaled S (staging area dead)
  #pragma unroll
  for(int g=0; g<G; g++){
    const int nl = wid*G + g;
    const float dv = 1.f/fmaxf((float)(rs_s[nl+1]-rs_s[nl]), 1.f);
    const v2f dv2 = v2f{dv, dv};
    #pragma unroll
    for(int p=0;p<PP;p++)
      #pragma unroll
      for(int u=0;u<TI2;u++)
        *(v2f*)&S[(nl*PLEN + pw*PP + p)*IC + iw*TI + 2*u] = acc2[g][p][u]*dv2;
  }

  // ---- GEMM: slice[n][o] partial over this wave's k-range; coalesced W2 ----
  const int oq  = lane % OQ;
  const int kql = lane / OQ;
  const int o0  = oq*TO;
  const float* W2b = W2 + (size_t)split*K*OC + o0;

  auto LOADW = [&](int j, v2f (&wv2)[4][NP], float (&wvs)[4]){
    const int k4 = j*TSPL + wid*KQL + kql;
    #pragma unroll
    for(int r=0;r<4;r++){
      const float* wr = W2b + (size_t)(4*k4+r)*OC;
      if constexpr (TO==4){
        float4 a=*(const float4*)wr;
        wv2[r][0]=v2f{a.x,a.y}; wv2[r][1]=v2f{a.z,a.w};
      } else if constexpr (TO==3){
        wv2[r][0]=v2f{wr[0],wr[1]}; wvs[r]=wr[2];
      } else {
        float2 a=*(const float2*)wr;
        wv2[r][0]=v2f{a.x,a.y};
      }
    }
  };

  v2f outp2[BN][NP];
  float outs[BN];
  #pragma unroll
  for(int n=0;n<BN;n++){
    #pragma unroll
    for(int t=0;t<NP;t++) outp2[n][t]=v2f{0.f,0.f};
    outs[n]=0.f;
  }

  v2f wvA[4][NP], wvB[4][NP];
  float wsA[4], wsB[4];
  LOADW(0, wvA, wsA);     // W2 j=0 in flight across the barrier (independent of S)
  __syncthreads();        // S visible to all waves

  #pragma unroll 1
  for(int j=0;j<J;j+=2){
    LOADW(j+1, wvB, wsB); // prefetch while FMAs on wvA run
    {
      const int k4 = j*TSPL + wid*KQL + kql;
      #pragma unroll
      for(int n=0;n<BN;n++){
        float4 sv = *(const float4*)&S[n*K + 4*k4];
        v2f s0=v2f{sv.x,sv.x}, s1=v2f{sv.y,sv.y}, s2=v2f{sv.z,sv.z}, s3=v2f{sv.w,sv.w};
        #pragma unroll
        for(int t=0;t<NP;t++)
          outp2[n][t] += s0*wvA[0][t] + s1*wvA[1][t] + s2*wvA[2][t] + s3*wvA[3][t];
        if constexpr (TODD)
          outs[n] += sv.x*wsA[0] + sv.y*wsA[1] + sv.z*wsA[2] + sv.w*wsA[3];
      }
    }
    if(j+2<J) LOADW(j+2, wvA, wsA);   // prefetch while FMAs on wvB run
    {
      const int k4 = (j+1)*TSPL + wid*KQL + kql;
      #pragma unroll
      for(int n=0;n<BN;n++){
        float4 sv = *(const float4*)&S[n*K + 4*k4];
        v2f s0=v2f{sv.x,sv.x}, s1=v2f{sv.y,sv.y}, s2=v2f{sv.z,sv.z}, s3=v2f{sv.w,sv.w};
        #pragma unroll
        for(int t=0;t<NP;t++)
          outp2[n][t] += s0*wvB[0][t] + s1*wvB[1][t] + s2*wvB[2][t] + s3*wvB[3][t];
        if constexpr (TODD)
          outs[n] += sv.x*wsB[0] + sv.y*wsB[1] + sv.z*wsB[2] + sv.w*wsB[3];
      }
    }
  }

  // intra-wave reduce over kql lanes (masks OQ..32)
  #pragma unroll
  for(int m=OQ; m<64; m<<=1)
    #pragma unroll
    for(int n=0;n<BN;n++){
      #pragma unroll
      for(int t=0;t<NP;t++){
        outp2[n][t][0] += __shfl_xor(outp2[n][t][0], m, 64);
        outp2[n][t][1] += __shfl_xor(outp2[n][t][1], m, 64);
      }
      if constexpr (TODD) outs[n] += __shfl_xor(outs[n], m, 64);
    }

  // cross-wave combine through dead S: ONE part slice per split (round-8-verified)
  __syncthreads();   // all GEMM S-reads complete
  if(wid>0 && kql==0){
    #pragma unroll
    for(int n=0;n<BN;n++){
      #pragma unroll
      for(int t=0;t<NP;t++){
        S[((wid-1)*BN+n)*OC + o0 + 2*t]   = outp2[n][t][0];
        S[((wid-1)*BN+n)*OC + o0 + 2*t+1] = outp2[n][t][1];
      }
      if constexpr (TODD) S[((wid-1)*BN+n)*OC + o0 + TO-1] = outs[n];
    }
  }
  __syncthreads();
  if(wid==0 && kql==0){
    float* slice = part + (size_t)split*NN*OC;
    #pragma unroll
    for(int n=0;n<BN;n++){
      float tmp[TO];
      #pragma unroll
      for(int t=0;t<NP;t++){ tmp[2*t]=outp2[n][t][0]; tmp[2*t+1]=outp2[n][t][1]; }
      if constexpr (TODD) tmp[TO-1]=outs[n];
      #pragma unroll
      for(int w2=0;w2<3;w2++)
        #pragma unroll
        for(int t=0;t<TO;t++) tmp[t] += S[(w2*BN+n)*OC + o0 + t];
      float* dst = slice + (size_t)(n0+n)*OC + o0;
      if constexpr (TO==4){
        *(float4*)dst = make_float4(tmp[0],tmp[1],tmp[2],tmp[3]);
      } else if constexpr (TO==3){
        dst[0]=tmp[0]; dst[1]=tmp[1]; dst[2]=tmp[2];
      } else {
        *(float2*)dst = make_float2(tmp[0],tmp[1]);
      }
    }
  }
}

// ---------------- epilogue: y = relu(sum_s part[s] + x@root + xbar@b2 + bias) ----------------
// Grid-stride (round-8 aux win); SL = KS (combine cut slices 4x).
template<int IC, int OC, int SL>
__global__ void k_epi(const float* __restrict__ part, const float* __restrict__ x,
                      const float* __restrict__ xbar,
                      const float* __restrict__ root, const float* __restrict__ b2,
                      const float* __restrict__ bias, float* __restrict__ y)
{
  for(int idx = blockIdx.x*256 + threadIdx.x; idx < NN*OC; idx += gridDim.x*256){
    int n = idx/OC, o = idx - n*OC;
    float v = bias[o];
    #pragma unroll
    for(int s=0;s<SL;s++) v += part[(size_t)s*NN*OC + idx];
    #pragma unroll
    for(int i=0;i<IC;i++) v += x[(size_t)n*IC+i]*root[i*OC+o];
    #pragma unroll
    for(int i=0;i<IC;i++) v += xbar[(size_t)n*IC+i]*b2[i*OC+o];
    y[idx] = fmaxf(v, 0.f);
  }
}

// ---------------- set2set (2 steps) + final MLP, one wave per graph ----------------
__global__ void k_s2s(const float* __restrict__ xg, const int* __restrict__ batch,
  const float* __restrict__ Wih, const float* __restrict__ Whh,
  const float* __restrict__ bih, const float* __restrict__ bhh,
  const float* __restrict__ l1W, const float* __restrict__ l1b,
  const float* __restrict__ l2W, const float* __restrict__ l2b,
  const float* __restrict__ lfW, const float* __restrict__ lfb,
  float* __restrict__ out)
{
  int g = blockIdx.x, lane = threadIdx.x;
  __shared__ float hs[16], cs[16], qs[32], gs[64], rs[16];
  int r0 = lowerb(batch, NN, g);
  int r1 = lowerb(batch, NN, g+1);
  if(lane<16){ hs[lane]=0.f; cs[lane]=0.f; }
  if(lane<32) qs[lane]=0.f;
  __syncthreads();
  for(int step=0; step<2; step++){
    float gate = bih[lane] + bhh[lane];
    for(int k=0;k<32;k++) gate += qs[k]*Wih[lane*32+k];
    for(int k=0;k<16;k++) gate += hs[k]*Whh[lane*16+k];
    gs[lane] = gate;
    __syncthreads();
    if(lane<16){
      float ig = 1.f/(1.f+expf(-gs[lane]));
      float fg = 1.f/(1.f+expf(-gs[lane+16]));
      float gg = tanhf(gs[lane+32]);
      float og = 1.f/(1.f+expf(-gs[lane+48]));
      float cn = fg*cs[lane] + ig*gg;
      cs[lane] = cn;
      hs[lane] = og*tanhf(cn);
    }
    __syncthreads();
    float m = -1e30f;
    for(int n=r0+lane; n<r1; n+=64){
      float e=0.f;
      for(int k=0;k<16;k++) e += xg[n*16+k]*hs[k];
      m = fmaxf(m, e);
    }
    for(int d=1; d<64; d<<=1) m = fmaxf(m, __shfl_xor(m, d));
    float ssum = 0.f;
    float racc[16];
    #pragma unroll
    for(int k=0;k<16;k++) racc[k]=0.f;
    for(int n=r0+lane; n<r1; n+=64){
      float e=0.f, xv[16];
      #pragma unroll
      for(int k=0;k<16;k++){ xv[k]=xg[n*16+k]; e += xv[k]*hs[k]; }
      float a = expf(e - m);
      ssum += a;
      #pragma unroll
      for(int k=0;k<16;k++) racc[k] += a*xv[k];
    }
    for(int d=1; d<64; d<<=1) ssum += __shfl_xor(ssum, d);
    #pragma unroll
    for(int k=0;k<16;k++)
      for(int d=1; d<64; d<<=1) racc[k] += __shfl_xor(racc[k], d);
    ssum = fmaxf(ssum, 1e-16f);
    if(lane==0){
      #pragma unroll
      for(int k=0;k<16;k++) rs[k] = racc[k]/ssum;
    }
    __syncthreads();
    if(lane<16){ qs[lane]=hs[lane]; qs[16+lane]=rs[lane]; }
    __syncthreads();
  }
  if(lane<16){
    float v = l1b[lane];
    for(int k=0;k<32;k++) v += qs[k]*l1W[k*16+lane];
    gs[lane] = fmaxf(v,0.f);
  }
  __syncthreads();
  if(lane<8){
    float v = l2b[lane];
    for(int k=0;k<16;k++) v += gs[k]*l2W[k*8+lane];
    gs[32+lane] = fmaxf(v,0.f);
  }
  __syncthreads();
  if(lane==0){
    float v = lfb[0];
    for(int k=0;k<8;k++) v += gs[32+k]*lfW[k];
    out[g] = v;
  }
}

extern "C" void kernel_launch(void* const* d_in, const int* in_sizes, int n_in,
                              void* d_out, int out_size, void* d_ws, size_t ws_size,
                              hipStream_t stream) {
  const float* x0   = (const float*)d_in[0];
  const int*   ei   = (const int*)d_in[1];
  const float* ea   = (const float*)d_in[2];
  const int*   batch= (const int*)d_in[3];
  const float* c1W1 = (const float*)d_in[4];  const float* c1b1 = (const float*)d_in[5];
  const float* c1W2 = (const float*)d_in[6];  const float* c1b2 = (const float*)d_in[7];
  const float* c1rt = (const float*)d_in[8];  const float* c1bs = (const float*)d_in[9];
  const float* c2W1 = (const float*)d_in[10]; const float* c2b1 = (const float*)d_in[11];
  const float* c2W2 = (const float*)d_in[12]; const float* c2b2 = (const float*)d_in[13];
  const float* c2rt = (const float*)d_in[14]; const float* c2bs = (const float*)d_in[15];
  const float* c3W1 = (const float*)d_in[16]; const float* c3b1 = (const float*)d_in[17];
  const float* c3W2 = (const float*)d_in[18]; const float* c3b2 = (const float*)d_in[19];
  const float* c3rt = (const float*)d_in[20]; const float* c3bs = (const float*)d_in[21];
  const float* Wih  = (const float*)d_in[22]; const float* Whh  = (const float*)d_in[23];
  const float* bih  = (const float*)d_in[24]; const float* bhh  = (const float*)d_in[25];
  const float* l1W  = (const float*)d_in[26]; const float* l1b  = (const float*)d_in[27];
  const float* l2W  = (const float*)d_in[28]; const float* l2b  = (const float*)d_in[29];
  const float* lfW  = (const float*)d_in[30]; const float* lfb  = (const float*)d_in[31];
  float* out = (float*)d_out;

  const int* src = ei;
  const int* tgt = ei + NE;

  // workspace carve
  char* w = (char*)d_ws;
  auto carve = [&](size_t bytes)->void*{ void* p = (void*)w; w += (bytes + 255) & ~(size_t)255; return p; };
  int*   row_start = (int*)carve((NN+1)*sizeof(int));
  int*   cur       = (int*)carve(NN*sizeof(int));
  int*   es_src    = (int*)carve(NE*sizeof(int));
  float* es_ea     = (float*)carve((size_t)NE*16*sizeof(float));
  float* xbar      = (float*)carve((size_t)NN*48*sizeof(float));
  float* y1   = (float*)carve((size_t)NN*48*sizeof(float));
  float* y2   = (float*)carve((size_t)NN*32*sizeof(float));
  float* y3   = (float*)carve((size_t)NN*16*sizeof(float));
  float* part = (float*)carve((size_t)16*NN*48*sizeof(float)); // up to 16 slices

  // ---- CSR by tgt (+ fused ea gather)
  hipMemsetAsync(cur, 0, NN*sizeof(int), stream);
  k_count<<<(NE+255)/256, 256, 0, stream>>>(tgt, cur);
  k_scan<<<1, 1024, 0, stream>>>(cur, row_start);
  hipMemsetAsync(cur, 0, NN*sizeof(int), stream);
  k_place<<<(NE+255)/256, 256, 0, stream>>>(src, tgt, ea, row_start, cur, es_src, es_ea);

  // ---- layer 1: IC=16 OC=48 | PLEN=64 KS=2 BN=8 G=2 PP=4 TI=4 | OQ=16 TO=3 | PF, EB=64 (2 slices)
  k_layer<16,48,64,2,8,4,4,16,3,true,64><<<(NN/8)*2, 256, 0, stream>>>(
      x0, es_ea, es_src, row_start, c1W1, c1b1, c1W2, part, xbar);
  k_epi<16,48,2><<<2048, 256, 0, stream>>>(part, x0, xbar, c1rt, c1b2, c1bs, y1);

  // ---- layer 2: IC=48 OC=32 | PLEN=32 KS=4 BN=8 G=2 PP=4 TI=6 | OQ=8 TO=4 | PF, EB=128 (4 slices)
  k_layer<48,32,32,4,8,4,6,8,4,true,128><<<(NN/8)*4, 256, 0, stream>>>(
      y1, es_ea, es_src, row_start, c2W1, c2b1, c2W2, part, xbar);
  k_epi<48,32,4><<<2048, 256, 0, stream>>>(part, y1, xbar, c2rt, c2b2, c2bs, y2);

  // ---- layer 3: IC=32 OC=16 | PLEN=64 KS=2 BN=4 G=1 PP=4 TI=8 | OQ=4 TO=4 | PF, EB=64 (2 slices)
  k_layer<32,16,64,2,4,4,8,4,4,true,64><<<(NN/4)*2, 256, 0, stream>>>(
      y2, es_ea, es_src, row_start, c3W1, c3b1, c3W2, part, xbar);
  k_epi<32,16,2><<<2048, 256, 0, stream>>>(part, y2, xbar, c3rt, c3b2, c3bs, y3);

  // ---- set2set + MLP head
  k_s2s<<<NG, 64, 0, stream>>>(y3, batch, Wih, Whh, bih, bhh, l1W, l1b, l2W, l2b, lfW, lfb, out);
}

// Round 16
// 688.203 us; speedup vs baseline: 1.1130x; 1.1130x over previous
//
#include <hip/hip_runtime.h>

#define NN 20000
#define NE 200000
#define NG 512

typedef float v2f __attribute__((ext_vector_type(2)));

__device__ __forceinline__ int lowerb(const int* a, int n, int v){
  int lo=0, hi=n;
  while(lo<hi){ int m=(lo+hi)>>1; if(a[m]<v) lo=m+1; else hi=m; }
  return lo;
}

// async global->LDS copy, 16B per lane. LDS dest must be linear in lane order
// (wave-uniform base + lane*16).
template<int AUX>
__device__ __forceinline__ void gload_lds16(const float4* g, float4* l){
  __builtin_amdgcn_global_load_lds(
    (const __attribute__((address_space(1))) void*)(g),
    (__attribute__((address_space(3))) void*)(l), 16, 0, AUX);
}

// ---------------- counting sort by tgt -> CSR ----------------
__global__ void k_count(const int* __restrict__ tgt, int* __restrict__ cnt){
  int e = blockIdx.x*blockDim.x + threadIdx.x;
  if(e<NE) atomicAdd(&cnt[tgt[e]], 1);
}

__global__ void k_scan(const int* __restrict__ cnt, int* __restrict__ row_start){
  __shared__ int part[1024];
  int t = threadIdx.x;
  const int CH = (NN + 1023)/1024; // 20
  int i0 = t*CH;
  int s = 0;
  for(int j=0;j<CH;j++){ int i=i0+j; if(i<NN) s += cnt[i]; }
  part[t] = s; __syncthreads();
  for(int d=1; d<1024; d<<=1){
    int v = (t>=d) ? part[t-d] : 0;
    __syncthreads();
    part[t] += v;
    __syncthreads();
  }
  int run = (t==0) ? 0 : part[t-1];
  for(int j=0;j<CH;j++){ int i=i0+j; if(i<NN){ row_start[i]=run; run += cnt[i]; } }
  if(t==0) row_start[NN] = part[1023];
}

// place edges in CSR order AND gather edge_attr to CSR order (fused)
__global__ void k_place(const int* __restrict__ src, const int* __restrict__ tgt,
                        const float* __restrict__ ea,
                        const int* __restrict__ row_start, int* __restrict__ cur,
                        int* __restrict__ es_src, float* __restrict__ es_ea){
  int e = blockIdx.x*blockDim.x + threadIdx.x;
  if(e>=NE) return;
  int n = tgt[e];
  int pos = row_start[n] + atomicAdd(&cur[n],1);
  es_src[pos] = src[e];
  const float4* s = (const float4*)ea + (size_t)e*4;
  float4* d = (float4*)es_ea + (size_t)pos*4;
  d[0]=s[0]; d[1]=s[1]; d[2]=s[2]; d[3]=s[3];
}

// ---------------- fused NNConv layer ----------------
// Round 16: EXACT round-13 source restored (best measured: 692us end-to-end).
// Rounds 14 and 15 both attempted scatter-loop micro-opts (A/B register sets; dual
// if-constexpr instantiation) and BOTH spilled to scratch (WRITE 13.75 -> 242/263MB)
// with reported VGPR unchanged at 84 -- spills overflow past the allocation and are
// invisible in VGPR_Count. The round-13 scatter is on a register-allocation knife
// edge: DO NOT perturb its code shape.
// Structure: H-compute fused into staging (splits partition H columns -> zero
// recompute), xbar fused into split-0 scatter, packed v2f math throughout, dead-S
// cross-wave combine (ONE part slice per split), PF scatter prefetch w/ rotation
// (the movs are the price for bounded liveness -- rounds 1/14), W2-only ping-pong
// GEMM (round 2), BN=8 for L1/L2 (round 7), no min-waves>3 (rounds 4/5),
// exact-multiple staging regions (async-tail overlap = race).
// Healthy counters: L2 layer ~270us, FETCH ~64MB, WRITE ~13.75MB, VGPR 84, occ ~31%.
template<int IC, int OC, int PLEN, int KS, int BN, int PP, int TI, int OQ, int TO, bool PF, int EB>
__launch_bounds__(256, 3)
__global__ void k_layer(const float* __restrict__ x_in, const float* __restrict__ es_ea,
                        const int* __restrict__ es_src, const int* __restrict__ row_start,
                        const float* __restrict__ W1, const float* __restrict__ b1,
                        const float* __restrict__ W2, float* __restrict__ part,
                        float* __restrict__ xbar_out)
{
  constexpr int K    = PLEN*IC;
  constexpr int XV   = IC/4;
  constexpr int NIW  = IC/TI;
  constexpr int NPW  = PLEN/PP;
  constexpr int G    = BN/4;
  constexpr int KQL  = 64/OQ;
  constexpr int TSPL = 4*KQL;
  constexpr int J    = (K/4)/TSPL;
  constexpr int NEA  = EB/64;            // ea staging chunks (EB*16/4/256)
  constexpr int NX4  = (EB*XV)/256;      // xs staging chunks (exact)
  constexpr int TI2  = TI/2;
  constexpr int NP   = TO/2;
  constexpr bool TODD = (TO & 1);
  constexpr int HP   = PLEN/2;           // column pairs per H-compute thread
  constexpr int EPB2 = 256/HP;           // edges per packed H-compute iteration
  static_assert(TI%2==0, "packed scatter needs even TI");
  static_assert(256%HP==0, "packed H-compute mapping");
  static_assert(EB%64==0, "ea region must be exact 256-f4 chunks");
  static_assert((EB*XV)%256==0, "xs region must be exact 256-f4 chunks");
  static_assert(EB*(PLEN+16+IC) <= BN*K, "staging alias fits in S");
  static_assert(NPW*NIW==64, "wave tile covers 64 lanes");
  static_assert(G*PP*TI <= 48, "spill-safe accumulator");
  static_assert(OQ*TO==OC && (K/4)%TSPL==0, "gemm tiling");
  static_assert(J%2==0, "ping-pong needs even J");
  static_assert(3*BN*OC <= BN*K, "combine area fits in dead S");

  __shared__ __align__(16) float S[BN*K];
  __shared__ int rs_s[BN+1], ro[BN+1];

  float* hb  = S;                        // EB*PLEN computed H slice
  float* eas = S + EB*PLEN;              // EB*16 staged edge_attr
  float* xs  = S + EB*(PLEN+16);         // EB*IC staged x[src]

  const int tid = threadIdx.x;
  const int wid = tid>>6, lane = tid&63;
  const int split = blockIdx.x % KS;
  const int nb = blockIdx.x / KS;
  const int n0 = nb*BN;

  if(tid<=BN) rs_s[tid] = row_start[n0+tid];
  __syncthreads();
  const int estart = rs_s[0], eend = rs_s[BN];

  const int pw = lane / NIW;
  const int iw = lane - pw*NIW;
  const int c2 = tid % HP, erow = tid / HP;

  // per-split W1 column PAIR + bias pair (hoisted; coalesced loads)
  v2f w1cp[16];
  const v2f b1cp = *(const v2f*)&b1[split*PLEN + 2*c2];
  #pragma unroll
  for(int i=0;i<16;i++) w1cp[i] = *(const v2f*)&W1[i*128 + split*PLEN + 2*c2];

  v2f acc2[G][PP][TI2];
  v2f xsum2[G][TI2];
  #pragma unroll
  for(int g=0;g<G;g++){
    #pragma unroll
    for(int p=0;p<PP;p++)
      #pragma unroll
      for(int u=0;u<TI2;u++) acc2[g][p][u]=v2f{0.f,0.f};
    #pragma unroll
    for(int u=0;u<TI2;u++) xsum2[g][u]=v2f{0.f,0.f};
  }

  const float4* EA4 = (const float4*)es_ea;
  const float4* x4  = (const float4*)x_in;

  for(int bstart=estart; bstart<eend; bstart+=EB){
    const int ebc = min(EB, eend-bstart);
    if(tid<=BN){ int v = rs_s[tid]-bstart; ro[tid] = min(max(v,0), ebc); }
    const int ea_lim = ebc*4, xs_lim = ebc*XV;
    // pre-load gather indices (independent loads, issued together)
    int sn_r[NX4];
    #pragma unroll
    for(int c=0;c<NX4;c++){
      int jc = min(tid + c*256, xs_lim-1);
      sn_r[c] = es_src[bstart + jc/XV];
    }
    // async edge_attr -> eas (CSR-linear source)
    #pragma unroll
    for(int c=0;c<NEA;c++){
      int j = tid + c*256;
      int jc = min(j, ea_lim-1);
      gload_lds16<0>(EA4 + (size_t)bstart*4 + jc, ((float4*)eas) + j);
    }
    // async x[src] -> xs
    #pragma unroll
    for(int c=0;c<NX4;c++){
      int j = tid + c*256;
      int jc = min(j, xs_lim-1);
      int q = jc - (jc/XV)*XV;
      gload_lds16<0>(x4 + (size_t)sn_r[c]*XV + q, ((float4*)xs) + j);
    }
    __syncthreads();   // drains vmcnt (global_load_lds tracked there)

    // ---- compute H slice (packed column pairs): h[e][2c2..2c2+1] ----
    for(int ec = erow; ec < ebc; ec += EPB2){
      v2f h = b1cp;
      #pragma unroll
      for(int q=0;q<4;q++){
        float4 a = *(const float4*)&eas[ec*16 + 4*q];   // broadcast within group
        h += v2f{a.x,a.x}*w1cp[4*q+0];
        h += v2f{a.y,a.y}*w1cp[4*q+1];
        h += v2f{a.z,a.z}*w1cp[4*q+2];
        h += v2f{a.w,a.w}*w1cp[4*q+3];
      }
      h[0] = fmaxf(h[0],0.f); h[1] = fmaxf(h[1],0.f);
      *(v2f*)&hb[ec*PLEN + 2*c2] = h;
    }
    __syncthreads();

    // ---- wave-private scatter (only the owning wave touches its nodes' edges) ----
    if constexpr (PF){
      #pragma unroll
      for(int g=0; g<G; g++){
        const int nl = wid*G + g;
        const int a = ro[nl], b = ro[nl+1];
        if(a>=b) continue;
        float hv[PP]; v2f xv2[TI2];
        #pragma unroll
        for(int p=0;p<PP;p++) hv[p] = hb[a*PLEN + pw*PP + p];
        #pragma unroll
        for(int u=0;u<TI2;u++) xv2[u] = *(const v2f*)&xs[a*IC + iw*TI + 2*u];
        for(int e=a; e<b; e++){
          float hn[PP]; v2f xn2[TI2];
          if(e+1<b){
            #pragma unroll
            for(int p=0;p<PP;p++) hn[p] = hb[(e+1)*PLEN + pw*PP + p];
            #pragma unroll
            for(int u=0;u<TI2;u++) xn2[u] = *(const v2f*)&xs[(e+1)*IC + iw*TI + 2*u];
          }
          #pragma unroll
          for(int p=0;p<PP;p++){
            v2f h2 = v2f{hv[p], hv[p]};
            #pragma unroll
            for(int u=0;u<TI2;u++) acc2[g][p][u] += h2*xv2[u];
          }
          #pragma unroll
          for(int u=0;u<TI2;u++) xsum2[g][u] += xv2[u];
          #pragma unroll
          for(int p=0;p<PP;p++) hv[p]=hn[p];
          #pragma unroll
          for(int u=0;u<TI2;u++) xv2[u]=xn2[u];
        }
      }
    } else {
      #pragma unroll
      for(int g=0; g<G; g++){
        const int nl = wid*G + g;
        const int a = ro[nl], b = ro[nl+1];
        for(int e=a; e<b; e++){
          float hv[PP];
          #pragma unroll
          for(int p=0;p<PP;p++) hv[p] = hb[e*PLEN + pw*PP + p];
          v2f xv2[TI2];
          #pragma unroll
          for(int u=0;u<TI2;u++) xv2[u] = *(const v2f*)&xs[e*IC + iw*TI + 2*u];
          #pragma unroll
          for(int p=0;p<PP;p++){
            v2f h2 = v2f{hv[p], hv[p]};
            #pragma unroll
            for(int u=0;u<TI2;u++) acc2[g][p][u] += h2*xv2[u];
          }
          #pragma unroll
          for(int u=0;u<TI2;u++) xsum2[g][u] += xv2[u];
        }
      }
    }
    __syncthreads();
  }

  // xbar write (split 0 only; pw==0 lanes hold the full iw-slice sums)
  if(split==0 && pw==0){
    #pragma unroll
    for(int g=0;g<G;g++){
      const int nl = wid*G + g;
      const float dv = 1.f/fmaxf((float)(rs_s[nl+1]-rs_s[nl]), 1.f);
      #pragma unroll
      for(int u=0;u<TI2;u++){
        v2f r = xsum2[g][u]*v2f{dv,dv};
        *(v2f*)&xbar_out[(size_t)(n0+nl)*IC + iw*TI + 2*u] = r;
      }
    }
  }

  // dump scaled S (staging area dead)
  #pragma unroll
  for(int g=0; g<G; g++){
    const int nl = wid*G + g;
    const float dv = 1.f/fmaxf((float)(rs_s[nl+1]-rs_s[nl]), 1.f);
    const v2f dv2 = v2f{dv, dv};
    #pragma unroll
    for(int p=0;p<PP;p++)
      #pragma unroll
      for(int u=0;u<TI2;u++)
        *(v2f*)&S[(nl*PLEN + pw*PP + p)*IC + iw*TI + 2*u] = acc2[g][p][u]*dv2;
  }

  // ---- GEMM: slice[n][o] partial over this wave's k-range; coalesced W2 ----
  const int oq  = lane % OQ;
  const int kql = lane / OQ;
  const int o0  = oq*TO;
  const float* W2b = W2 + (size_t)split*K*OC + o0;

  auto LOADW = [&](int j, v2f (&wv2)[4][NP], float (&wvs)[4]){
    const int k4 = j*TSPL + wid*KQL + kql;
    #pragma unroll
    for(int r=0;r<4;r++){
      const float* wr = W2b + (size_t)(4*k4+r)*OC;
      if constexpr (TO==4){
        float4 a=*(const float4*)wr;
        wv2[r][0]=v2f{a.x,a.y}; wv2[r][1]=v2f{a.z,a.w};
      } else if constexpr (TO==3){
        wv2[r][0]=v2f{wr[0],wr[1]}; wvs[r]=wr[2];
      } else {
        float2 a=*(const float2*)wr;
        wv2[r][0]=v2f{a.x,a.y};
      }
    }
  };

  v2f outp2[BN][NP];
  float outs[BN];
  #pragma unroll
  for(int n=0;n<BN;n++){
    #pragma unroll
    for(int t=0;t<NP;t++) outp2[n][t]=v2f{0.f,0.f};
    outs[n]=0.f;
  }

  v2f wvA[4][NP], wvB[4][NP];
  float wsA[4], wsB[4];
  LOADW(0, wvA, wsA);     // W2 j=0 in flight across the barrier (independent of S)
  __syncthreads();        // S visible to all waves

  #pragma unroll 1
  for(int j=0;j<J;j+=2){
    LOADW(j+1, wvB, wsB); // prefetch while FMAs on wvA run
    {
      const int k4 = j*TSPL + wid*KQL + kql;
      #pragma unroll
      for(int n=0;n<BN;n++){
        float4 sv = *(const float4*)&S[n*K + 4*k4];
        v2f s0=v2f{sv.x,sv.x}, s1=v2f{sv.y,sv.y}, s2=v2f{sv.z,sv.z}, s3=v2f{sv.w,sv.w};
        #pragma unroll
        for(int t=0;t<NP;t++)
          outp2[n][t] += s0*wvA[0][t] + s1*wvA[1][t] + s2*wvA[2][t] + s3*wvA[3][t];
        if constexpr (TODD)
          outs[n] += sv.x*wsA[0] + sv.y*wsA[1] + sv.z*wsA[2] + sv.w*wsA[3];
      }
    }
    if(j+2<J) LOADW(j+2, wvA, wsA);   // prefetch while FMAs on wvB run
    {
      const int k4 = (j+1)*TSPL + wid*KQL + kql;
      #pragma unroll
      for(int n=0;n<BN;n++){
        float4 sv = *(const float4*)&S[n*K + 4*k4];
        v2f s0=v2f{sv.x,sv.x}, s1=v2f{sv.y,sv.y}, s2=v2f{sv.z,sv.z}, s3=v2f{sv.w,sv.w};
        #pragma unroll
        for(int t=0;t<NP;t++)
          outp2[n][t] += s0*wvB[0][t] + s1*wvB[1][t] + s2*wvB[2][t] + s3*wvB[3][t];
        if constexpr (TODD)
          outs[n] += sv.x*wsB[0] + sv.y*wsB[1] + sv.z*wsB[2] + sv.w*wsB[3];
      }
    }
  }

  // intra-wave reduce over kql lanes (masks OQ..32)
  #pragma unroll
  for(int m=OQ; m<64; m<<=1)
    #pragma unroll
    for(int n=0;n<BN;n++){
      #pragma unroll
      for(int t=0;t<NP;t++){
        outp2[n][t][0] += __shfl_xor(outp2[n][t][0], m, 64);
        outp2[n][t][1] += __shfl_xor(outp2[n][t][1], m, 64);
      }
      if constexpr (TODD) outs[n] += __shfl_xor(outs[n], m, 64);
    }

  // cross-wave combine through dead S: ONE part slice per split (round-8-verified)
  __syncthreads();   // all GEMM S-reads complete
  if(wid>0 && kql==0){
    #pragma unroll
    for(int n=0;n<BN;n++){
      #pragma unroll
      for(int t=0;t<NP;t++){
        S[((wid-1)*BN+n)*OC + o0 + 2*t]   = outp2[n][t][0];
        S[((wid-1)*BN+n)*OC + o0 + 2*t+1] = outp2[n][t][1];
      }
      if constexpr (TODD) S[((wid-1)*BN+n)*OC + o0 + TO-1] = outs[n];
    }
  }
  __syncthreads();
  if(wid==0 && kql==0){
    float* slice = part + (size_t)split*NN*OC;
    #pragma unroll
    for(int n=0;n<BN;n++){
      float tmp[TO];
      #pragma unroll
      for(int t=0;t<NP;t++){ tmp[2*t]=outp2[n][t][0]; tmp[2*t+1]=outp2[n][t][1]; }
      if constexpr (TODD) tmp[TO-1]=outs[n];
      #pragma unroll
      for(int w2=0;w2<3;w2++)
        #pragma unroll
        for(int t=0;t<TO;t++) tmp[t] += S[(w2*BN+n)*OC + o0 + t];
      float* dst = slice + (size_t)(n0+n)*OC + o0;
      if constexpr (TO==4){
        *(float4*)dst = make_float4(tmp[0],tmp[1],tmp[2],tmp[3]);
      } else if constexpr (TO==3){
        dst[0]=tmp[0]; dst[1]=tmp[1]; dst[2]=tmp[2];
      } else {
        *(float2*)dst = make_float2(tmp[0],tmp[1]);
      }
    }
  }
}

// ---------------- epilogue: y = relu(sum_s part[s] + x@root + xbar@b2 + bias) ----------------
// Grid-stride (round-8 aux win); SL = KS (combine cut slices 4x).
template<int IC, int OC, int SL>
__global__ void k_epi(const float* __restrict__ part, const float* __restrict__ x,
                      const float* __restrict__ xbar,
                      const float* __restrict__ root, const float* __restrict__ b2,
                      const float* __restrict__ bias, float* __restrict__ y)
{
  for(int idx = blockIdx.x*256 + threadIdx.x; idx < NN*OC; idx += gridDim.x*256){
    int n = idx/OC, o = idx - n*OC;
    float v = bias[o];
    #pragma unroll
    for(int s=0;s<SL;s++) v += part[(size_t)s*NN*OC + idx];
    #pragma unroll
    for(int i=0;i<IC;i++) v += x[(size_t)n*IC+i]*root[i*OC+o];
    #pragma unroll
    for(int i=0;i<IC;i++) v += xbar[(size_t)n*IC+i]*b2[i*OC+o];
    y[idx] = fmaxf(v, 0.f);
  }
}

// ---------------- set2set (2 steps) + final MLP, one wave per graph ----------------
__global__ void k_s2s(const float* __restrict__ xg, const int* __restrict__ batch,
  const float* __restrict__ Wih, const float* __restrict__ Whh,
  const float* __restrict__ bih, const float* __restrict__ bhh,
  const float* __restrict__ l1W, const float* __restrict__ l1b,
  const float* __restrict__ l2W, const float* __restrict__ l2b,
  const float* __restrict__ lfW, const float* __restrict__ lfb,
  float* __restrict__ out)
{
  int g = blockIdx.x, lane = threadIdx.x;
  __shared__ float hs[16], cs[16], qs[32], gs[64], rs[16];
  int r0 = lowerb(batch, NN, g);
  int r1 = lowerb(batch, NN, g+1);
  if(lane<16){ hs[lane]=0.f; cs[lane]=0.f; }
  if(lane<32) qs[lane]=0.f;
  __syncthreads();
  for(int step=0; step<2; step++){
    float gate = bih[lane] + bhh[lane];
    for(int k=0;k<32;k++) gate += qs[k]*Wih[lane*32+k];
    for(int k=0;k<16;k++) gate += hs[k]*Whh[lane*16+k];
    gs[lane] = gate;
    __syncthreads();
    if(lane<16){
      float ig = 1.f/(1.f+expf(-gs[lane]));
      float fg = 1.f/(1.f+expf(-gs[lane+16]));
      float gg = tanhf(gs[lane+32]);
      float og = 1.f/(1.f+expf(-gs[lane+48]));
      float cn = fg*cs[lane] + ig*gg;
      cs[lane] = cn;
      hs[lane] = og*tanhf(cn);
    }
    __syncthreads();
    float m = -1e30f;
    for(int n=r0+lane; n<r1; n+=64){
      float e=0.f;
      for(int k=0;k<16;k++) e += xg[n*16+k]*hs[k];
      m = fmaxf(m, e);
    }
    for(int d=1; d<64; d<<=1) m = fmaxf(m, __shfl_xor(m, d));
    float ssum = 0.f;
    float racc[16];
    #pragma unroll
    for(int k=0;k<16;k++) racc[k]=0.f;
    for(int n=r0+lane; n<r1; n+=64){
      float e=0.f, xv[16];
      #pragma unroll
      for(int k=0;k<16;k++){ xv[k]=xg[n*16+k]; e += xv[k]*hs[k]; }
      float a = expf(e - m);
      ssum += a;
      #pragma unroll
      for(int k=0;k<16;k++) racc[k] += a*xv[k];
    }
    for(int d=1; d<64; d<<=1) ssum += __shfl_xor(ssum, d);
    #pragma unroll
    for(int k=0;k<16;k++)
      for(int d=1; d<64; d<<=1) racc[k] += __shfl_xor(racc[k], d);
    ssum = fmaxf(ssum, 1e-16f);
    if(lane==0){
      #pragma unroll
      for(int k=0;k<16;k++) rs[k] = racc[k]/ssum;
    }
    __syncthreads();
    if(lane<16){ qs[lane]=hs[lane]; qs[16+lane]=rs[lane]; }
    __syncthreads();
  }
  if(lane<16){
    float v = l1b[lane];
    for(int k=0;k<32;k++) v += qs[k]*l1W[k*16+lane];
    gs[lane] = fmaxf(v,0.f);
  }
  __syncthreads();
  if(lane<8){
    float v = l2b[lane];
    for(int k=0;k<16;k++) v += gs[k]*l2W[k*8+lane];
    gs[32+lane] = fmaxf(v,0.f);
  }
  __syncthreads();
  if(lane==0){
    float v = lfb[0];
    for(int k=0;k<8;k++) v += gs[32+k]*lfW[k];
    out[g] = v;
  }
}

extern "C" void kernel_launch(void* const* d_in, const int* in_sizes, int n_in,
                              void* d_out, int out_size, void* d_ws, size_t ws_size,
                              hipStream_t stream) {
  const float* x0   = (const float*)d_in[0];
  const int*   ei   = (const int*)d_in[1];
  const float* ea   = (const float*)d_in[2];
  const int*   batch= (const int*)d_in[3];
  const float* c1W1 = (const float*)d_in[4];  const float* c1b1 = (const float*)d_in[5];
  const float* c1W2 = (const float*)d_in[6];  const float* c1b2 = (const float*)d_in[7];
  const float* c1rt = (const float*)d_in[8];  const float* c1bs = (const float*)d_in[9];
  const float* c2W1 = (const float*)d_in[10]; const float* c2b1 = (const float*)d_in[11];
  const float* c2W2 = (const float*)d_in[12]; const float* c2b2 = (const float*)d_in[13];
  const float* c2rt = (const float*)d_in[14]; const float* c2bs = (const float*)d_in[15];
  const float* c3W1 = (const float*)d_in[16]; const float* c3b1 = (const float*)d_in[17];
  const float* c3W2 = (const float*)d_in[18]; const float* c3b2 = (const float*)d_in[19];
  const float* c3rt = (const float*)d_in[20]; const float* c3bs = (const float*)d_in[21];
  const float* Wih  = (const float*)d_in[22]; const float* Whh  = (const float*)d_in[23];
  const float* bih  = (const float*)d_in[24]; const float* bhh  = (const float*)d_in[25];
  const float* l1W  = (const float*)d_in[26]; const float* l1b  = (const float*)d_in[27];
  const float* l2W  = (const float*)d_in[28]; const float* l2b  = (const float*)d_in[29];
  const float* lfW  = (const float*)d_in[30]; const float* lfb  = (const float*)d_in[31];
  float* out = (float*)d_out;

  const int* src = ei;
  const int* tgt = ei + NE;

  // workspace carve
  char* w = (char*)d_ws;
  auto carve = [&](size_t bytes)->void*{ void* p = (void*)w; w += (bytes + 255) & ~(size_t)255; return p; };
  int*   row_start = (int*)carve((NN+1)*sizeof(int));
  int*   cur       = (int*)carve(NN*sizeof(int));
  int*   es_src    = (int*)carve(NE*sizeof(int));
  float* es_ea     = (float*)carve((size_t)NE*16*sizeof(float));
  float* xbar      = (float*)carve((size_t)NN*48*sizeof(float));
  float* y1   = (float*)carve((size_t)NN*48*sizeof(float));
  float* y2   = (float*)carve((size_t)NN*32*sizeof(float));
  float* y3   = (float*)carve((size_t)NN*16*sizeof(float));
  float* part = (float*)carve((size_t)16*NN*48*sizeof(float)); // up to 16 slices

  // ---- CSR by tgt (+ fused ea gather)
  hipMemsetAsync(cur, 0, NN*sizeof(int), stream);
  k_count<<<(NE+255)/256, 256, 0, stream>>>(tgt, cur);
  k_scan<<<1, 1024, 0, stream>>>(cur, row_start);
  hipMemsetAsync(cur, 0, NN*sizeof(int), stream);
  k_place<<<(NE+255)/256, 256, 0, stream>>>(src, tgt, ea, row_start, cur, es_src, es_ea);

  // ---- layer 1: IC=16 OC=48 | PLEN=64 KS=2 BN=8 G=2 PP=4 TI=4 | OQ=16 TO=3 | PF, EB=64 (2 slices)
  k_layer<16,48,64,2,8,4,4,16,3,true,64><<<(NN/8)*2, 256, 0, stream>>>(
      x0, es_ea, es_src, row_start, c1W1, c1b1, c1W2, part, xbar);
  k_epi<16,48,2><<<2048, 256, 0, stream>>>(part, x0, xbar, c1rt, c1b2, c1bs, y1);

  // ---- layer 2: IC=48 OC=32 | PLEN=32 KS=4 BN=8 G=2 PP=4 TI=6 | OQ=8 TO=4 | PF, EB=128 (4 slices)
  k_layer<48,32,32,4,8,4,6,8,4,true,128><<<(NN/8)*4, 256, 0, stream>>>(
      y1, es_ea, es_src, row_start, c2W1, c2b1, c2W2, part, xbar);
  k_epi<48,32,4><<<2048, 256, 0, stream>>>(part, y1, xbar, c2rt, c2b2, c2bs, y2);

  // ---- layer 3: IC=32 OC=16 | PLEN=64 KS=2 BN=4 G=1 PP=4 TI=8 | OQ=4 TO=4 | PF, EB=64 (2 slices)
  k_layer<32,16,64,2,4,4,8,4,4,true,64><<<(NN/4)*2, 256, 0, stream>>>(
      y2, es_ea, es_src, row_start, c3W1, c3b1, c3W2, part, xbar);
  k_epi<32,16,2><<<2048, 256, 0, stream>>>(part, y2, xbar, c3rt, c3b2, c3bs, y3);

  // ---- set2set + MLP head
  k_s2s<<<NG, 64, 0, stream>>>(y3, batch, Wih, Whh, bih, bhh, l1W, l1b, l2W, l2b, lfW, lfb, out);
}